// Round 2
// baseline (934.344 us; speedup 1.0000x reference)
//
#include <hip/hip_runtime.h>
#include <stdint.h>

typedef __bf16 bf16_t;
typedef __bf16 bf16x8 __attribute__((ext_vector_type(8)));
typedef __bf16 bf16x4 __attribute__((ext_vector_type(4)));
typedef float f32x4 __attribute__((ext_vector_type(4)));
typedef unsigned int u32;

#define DEVINL static __device__ __forceinline__

constexpr int BB = 4;
constexpr int SEQ = 2048;
constexpr int HID = 1024;
constexpr int NL = 4;
constexpr int MR = BB * SEQ;  // 8192
constexpr float LN_EPS = 1e-5f;
constexpr float MASK_NEG = -1e9f;

DEVINL f32x4 mfma16x16x32(bf16x8 a, bf16x8 b, f32x4 c) {
  return __builtin_amdgcn_mfma_f32_16x16x32_bf16(a, b, c, 0, 0, 0);
}

// async global->LDS, 16B per lane. LDS dest must be wave-uniform base;
// HW writes base + lane*16. Global src is per-lane.
DEVINL void gload_lds16(const bf16_t* g, bf16_t* l) {
  __builtin_amdgcn_global_load_lds(
      (const __attribute__((address_space(1))) u32*)g,
      (__attribute__((address_space(3))) u32*)l, 16, 0, 0);
}

// ---------------------------------------------------------------------------
// NT GEMM: C[M,N] = A[M,K] * B[N,K]^T. 128x128 tile, BK=32, 256 threads
// (4 waves 2x2), each wave owns 64x64 = 4x4 fragments of 16x16x32 MFMA.
// Staging: global_load_lds dwordx4 (m97 structure). LDS [128][32] bf16 linear,
// thread t <-> tile byte offset t*16 within each 4KB pass (2 passes/tile).
// EPI 0: QKV  — z in {0,1,2} selects (W,bias,out); out bf16 = acc + bias
// EPI 1: QK^T — z = batch; out bf16 = acc * scale
// EPI 2: PV   — z = batch; out f32  = acc
// ---------------------------------------------------------------------------
template <int EPI>
__global__ __launch_bounds__(256) void gemm_nt(
    const bf16_t* __restrict__ Abase, const bf16_t* __restrict__ Bm0,
    const bf16_t* __restrict__ Bm1, const bf16_t* __restrict__ Bm2,
    const float* __restrict__ bias0, const float* __restrict__ bias1,
    const float* __restrict__ bias2, bf16_t* __restrict__ out0,
    bf16_t* __restrict__ out1, bf16_t* __restrict__ out2,
    float* __restrict__ outfp, int M, int N, int K, float scale,
    size_t aStr, size_t bStr, size_t cStr) {
  __shared__ bf16_t lA[128 * 32];
  __shared__ bf16_t lB[128 * 32];

  const int t = threadIdx.x;
  const int wave = t >> 6;
  const int lane = t & 63;
  const int wm = wave >> 1;
  const int wn = wave & 1;
  const int z = blockIdx.z;
  const int brow = blockIdx.x * 128;
  const int bcol = blockIdx.y * 128;

  const bf16_t* A = Abase + (size_t)z * aStr;
  const bf16_t* Bp;
  const float* bias = nullptr;
  bf16_t* outb = nullptr;
  float* outf = nullptr;
  if (EPI == 0) {
    Bp = (z == 0) ? Bm0 : (z == 1) ? Bm1 : Bm2;
    bias = (z == 0) ? bias0 : (z == 1) ? bias1 : bias2;
    outb = (z == 0) ? out0 : (z == 1) ? out1 : out2;
  } else if (EPI == 1) {
    Bp = Bm0 + (size_t)z * bStr;
    outb = out0 + (size_t)z * cStr;
  } else {
    Bp = Bm0 + (size_t)z * bStr;
    outf = outfp + (size_t)z * cStr;
  }

  // staging map: thread t covers tile row (t>>2), k-chunk (t&3)*8 (pass 0);
  // pass 1 adds 64 rows. LDS linear [128][32]: byte off = pass*4096 + t*16.
  const int sRow = t >> 2;
  const int sCol = (t & 3) * 8;
  const bf16_t* gA = A + (size_t)(brow + sRow) * K + sCol;
  const bf16_t* gB = Bp + (size_t)(bcol + sRow) * K + sCol;
  const size_t rowHop = (size_t)64 * K;

  // wave-uniform LDS bases (bf16 elems): pass p at p*2048 + wave*512
  bf16_t* aDst = lA + wave * 512;
  bf16_t* bDst = lB + wave * 512;

  const int fr = lane & 15;
  const int kb = lane >> 4;
  const bf16_t* aRd = lA + (wm * 64 + fr) * 32 + kb * 8;
  const bf16_t* bRd = lB + (wn * 64 + fr) * 32 + kb * 8;

  f32x4 acc[4][4] = {};

  for (int k0 = 0; k0 < K; k0 += 32) {
    __syncthreads();  // previous iteration's LDS reads complete
    gload_lds16(gA + k0, aDst);
    gload_lds16(gA + k0 + rowHop, aDst + 2048);
    gload_lds16(gB + k0, bDst);
    gload_lds16(gB + k0 + rowHop, bDst + 2048);
    __syncthreads();  // compiler drains vmcnt(0) before barrier: tile visible
    bf16x8 af[4], bfv[4];
#pragma unroll
    for (int m = 0; m < 4; ++m) af[m] = *(const bf16x8*)(aRd + m * 512);
#pragma unroll
    for (int n = 0; n < 4; ++n) bfv[n] = *(const bf16x8*)(bRd + n * 512);
#pragma unroll
    for (int m = 0; m < 4; ++m)
#pragma unroll
      for (int n = 0; n < 4; ++n)
        acc[m][n] = mfma16x16x32(af[m], bfv[n], acc[m][n]);
  }

  // C/D layout (m89-verified): col = lane&15, row = (lane>>4)*4 + j
  const int cr0 = brow + wm * 64 + (lane >> 4) * 4;
  const int cc0 = bcol + wn * 64 + fr;
#pragma unroll
  for (int n = 0; n < 4; ++n) {
    const int col = cc0 + n * 16;
    float badd = 0.f;
    if (EPI == 0) badd = bias[col];
#pragma unroll
    for (int m = 0; m < 4; ++m) {
      const int row = cr0 + m * 16;
#pragma unroll
      for (int j = 0; j < 4; ++j) {
        const float vv = acc[m][n][j];
        if (EPI == 0)
          outb[(size_t)(row + j) * N + col] = (bf16_t)(vv + badd);
        else if (EPI == 1)
          outb[(size_t)(row + j) * N + col] = (bf16_t)(vv * scale);
        else
          outf[(size_t)(row + j) * N + col] = vv;
      }
    }
  }
}

// ---------------------------------------------------------------------------
__global__ __launch_bounds__(256) void cast_f32_bf16(
    const float* __restrict__ in, bf16_t* __restrict__ out, long n4) {
  const long stride = (long)gridDim.x * blockDim.x;
  for (long i = (long)blockIdx.x * blockDim.x + threadIdx.x; i < n4;
       i += stride) {
    f32x4 x = *(const f32x4*)(in + i * 4);
    bf16x4 o;
#pragma unroll
    for (int j = 0; j < 4; ++j) o[j] = (bf16_t)x[j];
    *(bf16x4*)(out + i * 4) = o;
  }
}

// v [z][SEQ][HID] -> vT [z][HID][SEQ]
__global__ __launch_bounds__(256) void transpose_bf16_k(
    const bf16_t* __restrict__ in, bf16_t* __restrict__ out) {
  __shared__ bf16_t tile[64][72];  // pad to dodge bank conflicts
  const int z = blockIdx.z;
  const bf16_t* src = in + (size_t)z * SEQ * HID;
  bf16_t* dst = out + (size_t)z * SEQ * HID;
  const int r0 = blockIdx.x * 64;
  const int c0 = blockIdx.y * 64;
  const int t = threadIdx.x;
  const int tx = t & 7;
  const int ty = t >> 3;  // 0..31
#pragma unroll
  for (int i = 0; i < 2; ++i) {
    const int r = ty + i * 32;
    bf16x8 vv = *(const bf16x8*)(src + (size_t)(r0 + r) * HID + c0 + tx * 8);
    *(bf16x8*)&tile[r][tx * 8] = vv;
  }
  __syncthreads();
#pragma unroll
  for (int i = 0; i < 2; ++i) {
    const int c = ty + i * 32;
    bf16x8 ov;
#pragma unroll
    for (int j = 0; j < 8; ++j) ov[j] = tile[tx * 8 + j][c];
    *(bf16x8*)(dst + (size_t)(c0 + c) * SEQ + r0 + tx * 8) = ov;
  }
}

// in-place masked softmax over rows of [B*S, S] bf16
__global__ __launch_bounds__(256) void softmax_rows(
    bf16_t* __restrict__ sc, const int* __restrict__ mask) {
  const int row = blockIdx.x;
  const int b = row >> 11;  // row / SEQ
  bf16_t* p = sc + (size_t)row * SEQ;
  const int* mrow = mask + (size_t)b * SEQ;
  const int t = threadIdx.x;
  const int wave = t >> 6;
  const int lane = t & 63;

  bf16x8 v = *(const bf16x8*)(p + t * 8);
  const int4 m0 = *(const int4*)(mrow + t * 8);
  const int4 m1 = *(const int4*)(mrow + t * 8 + 4);
  const int mk[8] = {m0.x, m0.y, m0.z, m0.w, m1.x, m1.y, m1.z, m1.w};

  float vals[8];
  float mx = -3.4e38f;
#pragma unroll
  for (int j = 0; j < 8; ++j) {
    float s = (float)v[j];
    if (mk[j] == 0) s = MASK_NEG;
    vals[j] = s;
    mx = fmaxf(mx, s);
  }
#pragma unroll
  for (int off = 32; off > 0; off >>= 1)
    mx = fmaxf(mx, __shfl_xor(mx, off, 64));
  __shared__ float red[4];
  if (lane == 0) red[wave] = mx;
  __syncthreads();
  mx = fmaxf(fmaxf(red[0], red[1]), fmaxf(red[2], red[3]));
  __syncthreads();

  float sum = 0.f;
#pragma unroll
  for (int j = 0; j < 8; ++j) {
    vals[j] = __expf(vals[j] - mx);
    sum += vals[j];
  }
#pragma unroll
  for (int off = 32; off > 0; off >>= 1) sum += __shfl_xor(sum, off, 64);
  if (lane == 0) red[wave] = sum;
  __syncthreads();
  sum = red[0] + red[1] + red[2] + red[3];
  const float inv = 1.f / sum;
  bf16x8 o;
#pragma unroll
  for (int j = 0; j < 8; ++j) o[j] = (bf16_t)(vals[j] * inv);
  *(bf16x8*)(p + t * 8) = o;
}

// y = x + attn; LayerNorm(y) -> xout (f32) and optionally bf16 copy
__global__ __launch_bounds__(256) void resid_ln(
    const float* __restrict__ attn, const float* __restrict__ xin,
    const float* __restrict__ lnw, const float* __restrict__ lnb,
    float* __restrict__ xout, bf16_t* __restrict__ xbout) {
  const int row = blockIdx.x;
  const int t = threadIdx.x;
  const int wave = t >> 6;
  const int lane = t & 63;
  const size_t base = (size_t)row * HID + t * 4;
  f32x4 av = *(const f32x4*)(attn + base);
  f32x4 xv = *(const f32x4*)(xin + base);
  f32x4 y;
#pragma unroll
  for (int j = 0; j < 4; ++j) y[j] = av[j] + xv[j];
  float s1 = y[0] + y[1] + y[2] + y[3];
  float s2 = y[0] * y[0] + y[1] * y[1] + y[2] * y[2] + y[3] * y[3];
#pragma unroll
  for (int off = 32; off > 0; off >>= 1) {
    s1 += __shfl_xor(s1, off, 64);
    s2 += __shfl_xor(s2, off, 64);
  }
  __shared__ float red[8];
  if (lane == 0) {
    red[wave] = s1;
    red[4 + wave] = s2;
  }
  __syncthreads();
  s1 = red[0] + red[1] + red[2] + red[3];
  s2 = red[4] + red[5] + red[6] + red[7];
  const float mu = s1 * (1.f / HID);
  const float var = s2 * (1.f / HID) - mu * mu;
  const float rs = rsqrtf(var + LN_EPS);
  const f32x4 wv = *(const f32x4*)(lnw + t * 4);
  const f32x4 bv = *(const f32x4*)(lnb + t * 4);
  f32x4 o;
#pragma unroll
  for (int j = 0; j < 4; ++j) o[j] = wv[j] * ((y[j] - mu) * rs) + bv[j];
  *(f32x4*)(xout + base) = o;
  if (xbout != nullptr) {
    bf16x4 ob;
#pragma unroll
    for (int j = 0; j < 4; ++j) ob[j] = (bf16_t)o[j];
    *(bf16x4*)(xbout + base) = ob;
  }
}

// ---------------------------------------------------------------------------
extern "C" void kernel_launch(void* const* d_in, const int* in_sizes, int n_in,
                              void* d_out, int out_size, void* d_ws,
                              size_t ws_size, hipStream_t stream) {
  const float* x_in = (const float*)d_in[0];
  const int* mask = (const int*)d_in[1];
  const float* Wq = (const float*)d_in[2];
  const float* bq = (const float*)d_in[3];
  const float* Wk = (const float*)d_in[4];
  const float* bk = (const float*)d_in[5];
  const float* Wv = (const float*)d_in[6];
  const float* bv = (const float*)d_in[7];
  const float* lnw = (const float*)d_in[8];
  const float* lnb = (const float*)d_in[9];
  float* out = (float*)d_out;

  char* ws = (char*)d_ws;
  size_t off = 0;
  auto alloc = [&](size_t bytes) {
    char* p = ws + off;
    off += (bytes + 255) & ~(size_t)255;
    return (void*)p;
  };
  const size_t LHH = (size_t)NL * HID * HID;
  bf16_t* wqb = (bf16_t*)alloc(LHH * 2);
  bf16_t* wkb = (bf16_t*)alloc(LHH * 2);
  bf16_t* wvb = (bf16_t*)alloc(LHH * 2);
  bf16_t* xb = (bf16_t*)alloc((size_t)MR * HID * 2);
  bf16_t* q = (bf16_t*)alloc((size_t)MR * HID * 2);
  bf16_t* k = (bf16_t*)alloc((size_t)MR * HID * 2);
  bf16_t* v = (bf16_t*)alloc((size_t)MR * HID * 2);
  bf16_t* vT = (bf16_t*)alloc((size_t)MR * HID * 2);
  bf16_t* scores = (bf16_t*)alloc((size_t)BB * SEQ * SEQ * 2);
  float* attn = (float*)alloc((size_t)MR * HID * 4);
  float* xbuf = (float*)alloc((size_t)MR * HID * 4);
  if (off > ws_size) return;  // workspace too small: bail deterministically

  // one-time casts
  cast_f32_bf16<<<2048, 256, 0, stream>>>(Wq, wqb, (long)(LHH / 4));
  cast_f32_bf16<<<2048, 256, 0, stream>>>(Wk, wkb, (long)(LHH / 4));
  cast_f32_bf16<<<2048, 256, 0, stream>>>(Wv, wvb, (long)(LHH / 4));
  cast_f32_bf16<<<2048, 256, 0, stream>>>(x_in, xb, (long)((size_t)MR * HID / 4));

  for (int l = 0; l < NL; ++l) {
    const size_t wo = (size_t)l * HID * HID;
    // QKV projections
    gemm_nt<0><<<dim3(MR / 128, HID / 128, 3), 256, 0, stream>>>(
        xb, wqb + wo, wkb + wo, wvb + wo, bq + (size_t)l * HID,
        bk + (size_t)l * HID, bv + (size_t)l * HID, q, k, v, nullptr, MR, HID,
        HID, 1.f, 0, 0, 0);
    // V^T for the PV GEMM (NT layout)
    transpose_bf16_k<<<dim3(SEQ / 64, HID / 64, BB), 256, 0, stream>>>(v, vT);
    // scores = q k^T / sqrt(H)
    gemm_nt<1><<<dim3(SEQ / 128, SEQ / 128, BB), 256, 0, stream>>>(
        q, k, nullptr, nullptr, nullptr, nullptr, nullptr, scores, nullptr,
        nullptr, nullptr, SEQ, SEQ, HID, 0.03125f, (size_t)SEQ * HID,
        (size_t)SEQ * HID, (size_t)SEQ * SEQ);
    // masked softmax (in place, bf16)
    softmax_rows<<<MR, 256, 0, stream>>>(scores, mask);
    // attn = probs @ v
    gemm_nt<2><<<dim3(SEQ / 128, HID / 128, BB), 256, 0, stream>>>(
        scores, vT, nullptr, nullptr, nullptr, nullptr, nullptr, nullptr,
        nullptr, nullptr, attn, SEQ, HID, SEQ, 1.f, (size_t)SEQ * SEQ,
        (size_t)HID * SEQ, (size_t)SEQ * HID);
    // residual + LayerNorm (+ bf16 recast of x for next layer)
    const float* xi = (l == 0) ? x_in : xbuf;
    float* xo = (l == NL - 1) ? out : xbuf;
    bf16_t* xbo = (l == NL - 1) ? nullptr : xb;
    resid_ln<<<MR, 256, 0, stream>>>(attn, xi, lnw + (size_t)l * HID,
                                     lnb + (size_t)l * HID, xo, xbo);
  }
}

// Round 3
// 729.515 us; speedup vs baseline: 1.2808x; 1.2808x over previous
//
#include <hip/hip_runtime.h>
#include <stdint.h>

typedef __bf16 bf16_t;
typedef __bf16 bf16x8 __attribute__((ext_vector_type(8)));
typedef __bf16 bf16x4 __attribute__((ext_vector_type(4)));
typedef float f32x4 __attribute__((ext_vector_type(4)));
typedef unsigned int u32;

#define DEVINL static __device__ __forceinline__

constexpr int BB = 4;
constexpr int SEQ = 2048;
constexpr int HID = 1024;
constexpr int NL = 4;
constexpr int MR = BB * SEQ;  // 8192
constexpr float LN_EPS = 1e-5f;
constexpr float MASK_NEG = -1e9f;

DEVINL f32x4 mfma16x16x32(bf16x8 a, bf16x8 b, f32x4 c) {
  return __builtin_amdgcn_mfma_f32_16x16x32_bf16(a, b, c, 0, 0, 0);
}

// async global->LDS, 16B/lane; LDS dest wave-uniform base + lane*16.
DEVINL void gload_lds16(const bf16_t* g, bf16_t* l) {
  __builtin_amdgcn_global_load_lds(
      (const __attribute__((address_space(1))) u32*)g,
      (__attribute__((address_space(3))) u32*)l, 16, 0, 0);
}

// ---------------------------------------------------------------------------
// 256x256 8-phase NT GEMM (plain-HIP port of the HK cdna4 schedule).
// BK=64, 512 threads (8 waves, 2Mx4N), per-wave C = 128x64 (8x4 frags).
// LDS: A[2buf][2half][128][64] + B same = 128 KiB, XOR slot-swizzle
// (slot ^= row&7 on 128B rows) applied on gload_lds SOURCE and ds_read addr.
// Staging: A_{kt+1} at phases 0-1, B_{kt+2} at phases 2-3 (safe: B buffer
// fully read at phase 0, A buffer is the other parity). vmcnt(4) once per
// K-tile (tail: vmcnt(0)). setprio(1) around each 16-MFMA cluster.
// EPI 0: QKV  z in {0,1,2} -> (W,bias,out); bf16 = acc + bias
// EPI 1: QK^T z = batch;    bf16 = acc * 1/sqrt(H)
// EPI 2: PV split-K2: z = batch*2+khalf; bf16 partial
// ---------------------------------------------------------------------------
template <int EPI>
__global__ __launch_bounds__(512, 2) void gemm8(
    const bf16_t* __restrict__ Ab, const bf16_t* __restrict__ B0,
    const bf16_t* __restrict__ B1, const bf16_t* __restrict__ B2,
    const float* __restrict__ bias0, const float* __restrict__ bias1,
    const float* __restrict__ bias2, bf16_t* __restrict__ o0,
    bf16_t* __restrict__ o1, bf16_t* __restrict__ o2) {
  constexpr int TM = (EPI == 0) ? 32 : 8;
  constexpr int TN = (EPI == 1) ? 8 : 4;
  constexpr int LDA = (EPI == 2) ? SEQ : HID;
  constexpr int LDB = (EPI == 2) ? SEQ : HID;
  constexpr int LDC = (EPI == 1) ? SEQ : HID;
  constexpr int NT = 16;  // K-tiles of 64 (all our K-extents are 1024)

  __shared__ bf16_t lA[2 * 16384];
  __shared__ bf16_t lB[2 * 16384];

  // bijective XCD swizzle (grid % 8 == 0 for all launches)
  const int nwg = gridDim.x;
  int Lb = blockIdx.x;
  Lb = (Lb & 7) * (nwg >> 3) + (Lb >> 3);
  const int z = Lb / (TM * TN);
  const int rem = Lb - z * (TM * TN);
  const int tm = rem / TN;
  const int tn = rem - tm * TN;
  const int brow = tm * 256, bcol = tn * 256;

  const bf16_t* A;
  const bf16_t* B;
  const float* bias = nullptr;
  bf16_t* outb = nullptr;
  if (EPI == 0) {
    A = Ab;
    B = (z == 0) ? B0 : (z == 1) ? B1 : B2;
    bias = (z == 0) ? bias0 : (z == 1) ? bias1 : bias2;
    outb = (z == 0) ? o0 : (z == 1) ? o1 : o2;
  } else if (EPI == 1) {
    A = Ab + (size_t)z * SEQ * HID;
    B = B0 + (size_t)z * SEQ * HID;
    outb = o0 + (size_t)z * SEQ * SEQ;
  } else {
    const int zb = z >> 1, kh = z & 1;
    A = Ab + (size_t)zb * SEQ * SEQ + kh * 1024;   // scores K-half
    B = B0 + (size_t)zb * HID * SEQ + kh * 1024;   // vT K-half
    outb = ((kh == 0) ? o0 : o1) + (size_t)zb * SEQ * HID;
  }

  const int t = threadIdx.x, wave = t >> 6, lane = t & 63;
  const int wm = wave >> 2, wn = wave & 3;
  const int fr = lane & 15, kb = lane >> 4;
  const int srow = t >> 3;                 // 0..63 (64 rows per gload call)
  const int cbk = (t & 7) ^ (srow & 7);    // pre-swizzled source slot
  const bf16_t* pAs = A + (size_t)(brow + srow) * LDA + cbk * 8;
  const bf16_t* pBs = B + (size_t)(bcol + srow) * LDB + cbk * 8;
  bf16_t* lAw = lA + wave * 512;
  bf16_t* lBw = lB + wave * 512;

#define SA_HALF(kt_, h_)                                                   \
  {                                                                        \
    bf16_t* d_ = lAw + ((kt_)&1) * 16384 + (h_)*8192;                      \
    const bf16_t* g_ = pAs + (size_t)((h_)*128) * LDA + (kt_)*64;          \
    gload_lds16(g_, d_);                                                   \
    gload_lds16(g_ + (size_t)64 * LDA, d_ + 4096);                         \
  }
#define SB_HALF(kt_, h_)                                                   \
  {                                                                        \
    bf16_t* d_ = lBw + ((kt_)&1) * 16384 + (h_)*8192;                      \
    const bf16_t* g_ = pBs + (size_t)((h_)*128) * LDB + (kt_)*64;          \
    gload_lds16(g_, d_);                                                   \
    gload_lds16(g_ + (size_t)64 * LDB, d_ + 4096);                         \
  }

  const char* lAc = (const char*)lA;
  const char* lBc = (const char*)lB;
  const int cX0 = ((kb ^ (fr & 7)) << 4);  // swizzled ds_read col (ks=0)
  const int cX1 = cX0 ^ 64;                // ks=1
  const int bRowOff = (wn & 1) * 64;

  f32x4 acc[8][4] = {};

  // prologue: A_0, B_0, B_1 (12 vmem/wave); wait all but B_1's 4
  SA_HALF(0, 0); SA_HALF(0, 1);
  SB_HALF(0, 0); SB_HALF(0, 1);
  SB_HALF(1, 0); SB_HALF(1, 1);
  asm volatile("s_waitcnt vmcnt(4)" ::: "memory");
  __builtin_amdgcn_s_barrier();

  for (int kt = 0; kt < NT; ++kt) {
    const char* aB = lAc + (size_t)(kt & 1) * 32768 + wm * 16384;
    const char* bB = lBc + (size_t)(kt & 1) * 32768 + (wn >> 1) * 16384;
    bf16x8 bf_[4][2];
#pragma unroll
    for (int p = 0; p < 4; ++p) {
      if (p == 0) {  // B-frags for the whole K-tile, kept in regs
#pragma unroll
        for (int n = 0; n < 4; ++n) {
          const int rb = (bRowOff + n * 16 + fr) * 128;
          bf_[n][0] = *(const bf16x8*)(bB + rb + cX0);
          bf_[n][1] = *(const bf16x8*)(bB + rb + cX1);
        }
      }
      const int ra0 = (p * 32 + fr) * 128;
      const int ra1 = (p * 32 + 16 + fr) * 128;
      bf16x8 a00 = *(const bf16x8*)(aB + ra0 + cX0);
      bf16x8 a01 = *(const bf16x8*)(aB + ra0 + cX1);
      bf16x8 a10 = *(const bf16x8*)(aB + ra1 + cX0);
      bf16x8 a11 = *(const bf16x8*)(aB + ra1 + cX1);
      if (p == 0 && kt + 1 < NT) SA_HALF(kt + 1, 0);
      if (p == 1 && kt + 1 < NT) SA_HALF(kt + 1, 1);
      if (p == 2 && kt + 2 < NT) SB_HALF(kt + 2, 0);
      if (p == 3 && kt + 2 < NT) SB_HALF(kt + 2, 1);
      __builtin_amdgcn_s_barrier();
      __builtin_amdgcn_s_setprio(1);
#pragma unroll
      for (int n = 0; n < 4; ++n) {
        acc[2 * p][n] = mfma16x16x32(a00, bf_[n][0], acc[2 * p][n]);
        acc[2 * p][n] = mfma16x16x32(a01, bf_[n][1], acc[2 * p][n]);
        acc[2 * p + 1][n] = mfma16x16x32(a10, bf_[n][0], acc[2 * p + 1][n]);
        acc[2 * p + 1][n] = mfma16x16x32(a11, bf_[n][1], acc[2 * p + 1][n]);
      }
      __builtin_amdgcn_s_setprio(0);
      if (p == 3) {  // once per K-tile; counted (never 0 until tail)
        if (kt < NT - 2)
          asm volatile("s_waitcnt vmcnt(4)" ::: "memory");
        else
          asm volatile("s_waitcnt vmcnt(0)" ::: "memory");
      }
      __builtin_amdgcn_s_barrier();
    }
  }

  // C/D layout (m89): col = lane&15, row = (lane>>4)*4 + j
  const int qr = lane >> 4;
  const int crow = brow + wm * 128 + qr * 4;
  const int ccol = bcol + wn * 64 + fr;
#pragma unroll
  for (int n = 0; n < 4; ++n) {
    const int col = ccol + n * 16;
    const float badd = (EPI == 0) ? bias[col] : 0.f;
#pragma unroll
    for (int m = 0; m < 8; ++m) {
      const int row = crow + m * 16;
#pragma unroll
      for (int j = 0; j < 4; ++j) {
        const float vv = acc[m][n][j];
        if (EPI == 0)
          outb[(size_t)(row + j) * LDC + col] = (bf16_t)(vv + badd);
        else if (EPI == 1)
          outb[(size_t)(row + j) * LDC + col] = (bf16_t)(vv * 0.03125f);
        else
          outb[(size_t)(row + j) * LDC + col] = (bf16_t)vv;
      }
    }
  }
#undef SA_HALF
#undef SB_HALF
}

// ---------------------------------------------------------------------------
__global__ __launch_bounds__(256) void cast_f32_bf16(
    const float* __restrict__ in, bf16_t* __restrict__ out, long n4) {
  const long stride = (long)gridDim.x * blockDim.x;
  for (long i = (long)blockIdx.x * blockDim.x + threadIdx.x; i < n4;
       i += stride) {
    f32x4 x = *(const f32x4*)(in + i * 4);
    bf16x4 o;
#pragma unroll
    for (int j = 0; j < 4; ++j) o[j] = (bf16_t)x[j];
    *(bf16x4*)(out + i * 4) = o;
  }
}

// v [z][SEQ][HID] -> vT [z][HID][SEQ]
__global__ __launch_bounds__(256) void transpose_bf16_k(
    const bf16_t* __restrict__ in, bf16_t* __restrict__ out) {
  __shared__ bf16_t tile[64][72];
  const int z = blockIdx.z;
  const bf16_t* src = in + (size_t)z * SEQ * HID;
  bf16_t* dst = out + (size_t)z * SEQ * HID;
  const int r0 = blockIdx.x * 64;
  const int c0 = blockIdx.y * 64;
  const int t = threadIdx.x;
  const int tx = t & 7;
  const int ty = t >> 3;
#pragma unroll
  for (int i = 0; i < 2; ++i) {
    const int r = ty + i * 32;
    bf16x8 vv = *(const bf16x8*)(src + (size_t)(r0 + r) * HID + c0 + tx * 8);
    *(bf16x8*)&tile[r][tx * 8] = vv;
  }
  __syncthreads();
#pragma unroll
  for (int i = 0; i < 2; ++i) {
    const int c = ty + i * 32;
    bf16x8 ov;
#pragma unroll
    for (int j = 0; j < 8; ++j) ov[j] = tile[tx * 8 + j][c];
    *(bf16x8*)(dst + (size_t)(c0 + c) * SEQ + r0 + tx * 8) = ov;
  }
}

// in-place masked softmax over rows of [B*S, S] bf16
__global__ __launch_bounds__(256) void softmax_rows(
    bf16_t* __restrict__ sc, const int* __restrict__ mask) {
  const int row = blockIdx.x;
  const int b = row >> 11;
  bf16_t* p = sc + (size_t)row * SEQ;
  const int* mrow = mask + (size_t)b * SEQ;
  const int t = threadIdx.x;
  const int wave = t >> 6;
  const int lane = t & 63;

  bf16x8 v = *(const bf16x8*)(p + t * 8);
  const int4 m0 = *(const int4*)(mrow + t * 8);
  const int4 m1 = *(const int4*)(mrow + t * 8 + 4);
  const int mk[8] = {m0.x, m0.y, m0.z, m0.w, m1.x, m1.y, m1.z, m1.w};

  float vals[8];
  float mx = -3.4e38f;
#pragma unroll
  for (int j = 0; j < 8; ++j) {
    float s = (float)v[j];
    if (mk[j] == 0) s = MASK_NEG;
    vals[j] = s;
    mx = fmaxf(mx, s);
  }
#pragma unroll
  for (int off = 32; off > 0; off >>= 1)
    mx = fmaxf(mx, __shfl_xor(mx, off, 64));
  __shared__ float red[4];
  if (lane == 0) red[wave] = mx;
  __syncthreads();
  mx = fmaxf(fmaxf(red[0], red[1]), fmaxf(red[2], red[3]));
  __syncthreads();

  float sum = 0.f;
#pragma unroll
  for (int j = 0; j < 8; ++j) {
    vals[j] = __expf(vals[j] - mx);
    sum += vals[j];
  }
#pragma unroll
  for (int off = 32; off > 0; off >>= 1) sum += __shfl_xor(sum, off, 64);
  if (lane == 0) red[wave] = sum;
  __syncthreads();
  sum = red[0] + red[1] + red[2] + red[3];
  const float inv = 1.f / sum;
  bf16x8 o;
#pragma unroll
  for (int j = 0; j < 8; ++j) o[j] = (bf16_t)(vals[j] * inv);
  *(bf16x8*)(p + t * 8) = o;
}

// y = x + attn0 + attn1 (bf16 split-K partials); LayerNorm(y) -> xout (+bf16)
__global__ __launch_bounds__(256) void resid_ln(
    const bf16_t* __restrict__ part0, const bf16_t* __restrict__ part1,
    const float* __restrict__ xin, const float* __restrict__ lnw,
    const float* __restrict__ lnb, float* __restrict__ xout,
    bf16_t* __restrict__ xbout) {
  const int row = blockIdx.x;
  const int t = threadIdx.x;
  const int wave = t >> 6;
  const int lane = t & 63;
  const size_t base = (size_t)row * HID + t * 4;
  const bf16x4 a0 = *(const bf16x4*)(part0 + base);
  const bf16x4 a1 = *(const bf16x4*)(part1 + base);
  const f32x4 xv = *(const f32x4*)(xin + base);
  f32x4 y;
#pragma unroll
  for (int j = 0; j < 4; ++j) y[j] = (float)a0[j] + (float)a1[j] + xv[j];
  float s1 = y[0] + y[1] + y[2] + y[3];
  float s2 = y[0] * y[0] + y[1] * y[1] + y[2] * y[2] + y[3] * y[3];
#pragma unroll
  for (int off = 32; off > 0; off >>= 1) {
    s1 += __shfl_xor(s1, off, 64);
    s2 += __shfl_xor(s2, off, 64);
  }
  __shared__ float red[8];
  if (lane == 0) {
    red[wave] = s1;
    red[4 + wave] = s2;
  }
  __syncthreads();
  s1 = red[0] + red[1] + red[2] + red[3];
  s2 = red[4] + red[5] + red[6] + red[7];
  const float mu = s1 * (1.f / HID);
  const float var = s2 * (1.f / HID) - mu * mu;
  const float rs = rsqrtf(var + LN_EPS);
  const f32x4 wv = *(const f32x4*)(lnw + t * 4);
  const f32x4 bv = *(const f32x4*)(lnb + t * 4);
  f32x4 o;
#pragma unroll
  for (int j = 0; j < 4; ++j) o[j] = wv[j] * ((y[j] - mu) * rs) + bv[j];
  *(f32x4*)(xout + base) = o;
  if (xbout != nullptr) {
    bf16x4 ob;
#pragma unroll
    for (int j = 0; j < 4; ++j) ob[j] = (bf16_t)o[j];
    *(bf16x4*)(xbout + base) = ob;
  }
}

// ---------------------------------------------------------------------------
extern "C" void kernel_launch(void* const* d_in, const int* in_sizes, int n_in,
                              void* d_out, int out_size, void* d_ws,
                              size_t ws_size, hipStream_t stream) {
  const float* x_in = (const float*)d_in[0];
  const int* mask = (const int*)d_in[1];
  const float* Wq = (const float*)d_in[2];
  const float* bq = (const float*)d_in[3];
  const float* Wk = (const float*)d_in[4];
  const float* bk = (const float*)d_in[5];
  const float* Wv = (const float*)d_in[6];
  const float* bv = (const float*)d_in[7];
  const float* lnw = (const float*)d_in[8];
  const float* lnb = (const float*)d_in[9];
  float* out = (float*)d_out;

  char* ws = (char*)d_ws;
  size_t off = 0;
  auto alloc = [&](size_t bytes) {
    char* p = ws + off;
    off += (bytes + 255) & ~(size_t)255;
    return (void*)p;
  };
  const size_t LHH = (size_t)NL * HID * HID;
  bf16_t* wqb = (bf16_t*)alloc(LHH * 2);
  bf16_t* wkb = (bf16_t*)alloc(LHH * 2);
  bf16_t* wvb = (bf16_t*)alloc(LHH * 2);
  bf16_t* xb = (bf16_t*)alloc((size_t)MR * HID * 2);
  bf16_t* q = (bf16_t*)alloc((size_t)MR * HID * 2);
  bf16_t* k = (bf16_t*)alloc((size_t)MR * HID * 2);
  bf16_t* v = (bf16_t*)alloc((size_t)MR * HID * 2);
  bf16_t* vT = (bf16_t*)alloc((size_t)MR * HID * 2);
  bf16_t* scores = (bf16_t*)alloc((size_t)BB * SEQ * SEQ * 2);
  bf16_t* attn0 = (bf16_t*)alloc((size_t)MR * HID * 2);
  bf16_t* attn1 = (bf16_t*)alloc((size_t)MR * HID * 2);
  float* xbuf = (float*)alloc((size_t)MR * HID * 4);
  if (off > ws_size) return;

  cast_f32_bf16<<<2048, 256, 0, stream>>>(Wq, wqb, (long)(LHH / 4));
  cast_f32_bf16<<<2048, 256, 0, stream>>>(Wk, wkb, (long)(LHH / 4));
  cast_f32_bf16<<<2048, 256, 0, stream>>>(Wv, wvb, (long)(LHH / 4));
  cast_f32_bf16<<<2048, 256, 0, stream>>>(x_in, xb, (long)((size_t)MR * HID / 4));

  for (int l = 0; l < NL; ++l) {
    const size_t wo = (size_t)l * HID * HID;
    // QKV projections: grid 3*32*4 = 384
    gemm8<0><<<384, 512, 0, stream>>>(xb, wqb + wo, wkb + wo, wvb + wo,
                                      bq + (size_t)l * HID, bk + (size_t)l * HID,
                                      bv + (size_t)l * HID, q, k, v);
    // V^T for the PV GEMM
    transpose_bf16_k<<<dim3(SEQ / 64, HID / 64, BB), 256, 0, stream>>>(v, vT);
    // scores = q k^T / sqrt(H): grid 4*8*8 = 256
    gemm8<1><<<256, 512, 0, stream>>>(q, k, nullptr, nullptr, nullptr, nullptr,
                                      nullptr, scores, nullptr, nullptr);
    // masked softmax (in place)
    softmax_rows<<<MR, 256, 0, stream>>>(scores, mask);
    // attn partials = probs @ v (split-K 2): grid 8*8*4 = 256
    gemm8<2><<<256, 512, 0, stream>>>(scores, vT, nullptr, nullptr, nullptr,
                                      nullptr, nullptr, attn0, attn1, nullptr);
    // residual + LayerNorm (+ bf16 recast for next layer)
    const float* xi = (l == 0) ? x_in : xbuf;
    float* xo = (l == NL - 1) ? out : xbuf;
    bf16_t* xbo = (l == NL - 1) ? nullptr : xb;
    resid_ln<<<MR, 256, 0, stream>>>(attn0, attn1, xi, lnw + (size_t)l * HID,
                                     lnb + (size_t)l * HID, xo, xbo);
  }
}